// Round 1
// baseline (141.061 us; speedup 1.0000x reference)
//
#include <hip/hip_runtime.h>
#include <cstdint>
#include <cstddef>

#define IC 512     // in_caps
#define IDM 768    // in_dim
#define KC 16      // num_caps
#define DC 64      // dim_caps
#define NB 128     // batch
#define NOUT 1024  // KC*DC

// ---- workspace layout (float offsets) ----
// p0/p1: split-K GEMM partials for combined (m rows 0..511, q rows 512..639)
static const size_t OFF_P0   = 0;          // 640*1024
static const size_t OFF_P1   = 655360;     // 640*1024
static const size_t OFF_A    = 0;          // 128*16*512  (overlaps P region; first written after row_stats)
static const size_t OFF_PD   = 1310720;    // 128*16*512  (p, then dsp in place)
static const size_t OFF_HM   = 2359296;    // 512*1024
static const size_t OFF_Y    = 2883584;    // 128*1024    (tmp_q, updated in place)
static const size_t OFF_V    = 3014656;    // 128*1024
static const size_t OFF_SUMM = 3145728;    // 8192
static const size_t OFF_INVX = 3153920;    // 8192
static const size_t OFF_SY   = 3162112;    // 2048
static const size_t OFF_INVY = 3164160;    // 2048
// total: 3166208 floats = 12.7 MB

// ===================== K1: fused [m;q] @ W_w^T, split-K=2 =====================
// BM=64, BN=64, BK=32, 256 thr, 4x4 micro-tile. LDS k-major (AsT[kk][row]) so
// frag reads are aligned ds_read_b128 with <=2-way bank aliasing (free).
__global__ __launch_bounds__(256) void k_gemm(
    const float* __restrict__ m, const float* __restrict__ q,
    const float* __restrict__ Ww, const float* __restrict__ Wb,
    float* __restrict__ p0, float* __restrict__ p1)
{
  __shared__ __align__(16) float AsT[32 * 68];
  __shared__ __align__(16) float BsT[32 * 68];
  const int t = threadIdx.x;
  const int tx = t & 15, ty = t >> 4;
  const int n0 = blockIdx.x * 64;
  const int crow0 = blockIdx.y * 64;   // combined row tile (0..639)
  const int z = blockIdx.z;            // k-split
  const int kb0 = z * 384;
  const float* src = (crow0 < IC) ? (m + (size_t)crow0 * IDM)
                                  : (q + (size_t)(crow0 - IC) * IDM);
  float* dst = (z ? p1 : p0) + (size_t)crow0 * NOUT;

  float acc[4][4] = {};
  for (int it = 0; it < 12; ++it) {
    const int kb = kb0 + it * 32;
    #pragma unroll
    for (int jj = 0; jj < 2; ++jj) {
      const int id = t + jj * 256;
      const int r = id >> 3;
      const int c4 = (id & 7) << 2;
      const float4 av = *(const float4*)&src[(size_t)r * IDM + kb + c4];
      AsT[(c4 + 0) * 68 + r] = av.x;
      AsT[(c4 + 1) * 68 + r] = av.y;
      AsT[(c4 + 2) * 68 + r] = av.z;
      AsT[(c4 + 3) * 68 + r] = av.w;
      const float4 bv = *(const float4*)&Ww[(size_t)(n0 + r) * IDM + kb + c4];
      BsT[(c4 + 0) * 68 + r] = bv.x;
      BsT[(c4 + 1) * 68 + r] = bv.y;
      BsT[(c4 + 2) * 68 + r] = bv.z;
      BsT[(c4 + 3) * 68 + r] = bv.w;
    }
    __syncthreads();
    #pragma unroll 8
    for (int kk = 0; kk < 32; ++kk) {
      const float4 a4 = *(const float4*)&AsT[kk * 68 + ty * 4];
      const float4 b4 = *(const float4*)&BsT[kk * 68 + tx * 4];
      const float am[4] = {a4.x, a4.y, a4.z, a4.w};
      const float bn[4] = {b4.x, b4.y, b4.z, b4.w};
      #pragma unroll
      for (int mi = 0; mi < 4; ++mi) {
        #pragma unroll
        for (int nj = 0; nj < 4; ++nj) acc[mi][nj] += am[mi] * bn[nj];
      }
    }
    __syncthreads();
  }
  float4 bias = make_float4(0.f, 0.f, 0.f, 0.f);
  if (z == 0) bias = *(const float4*)&Wb[n0 + tx * 4];
  #pragma unroll
  for (int mi = 0; mi < 4; ++mi) {
    float4 o;
    o.x = acc[mi][0] + bias.x; o.y = acc[mi][1] + bias.y;
    o.z = acc[mi][2] + bias.z; o.w = acc[mi][3] + bias.w;
    *(float4*)&dst[(size_t)(ty * 4 + mi) * NOUT + n0 + tx * 4] = o;
  }
}

// ===================== K2: sum split-K parts + per-row stats =====================
// One wave per 64-float row (i,k) or (b,k): writes summed row, sum, 1/||centered||.
__global__ __launch_bounds__(256) void k_rowstats(
    const float* __restrict__ pa, const float* __restrict__ pb,
    float* __restrict__ rows, float* __restrict__ sum_out, float* __restrict__ inv_out)
{
  const int w = blockIdx.x * 4 + (threadIdx.x >> 6);
  const int lane = threadIdx.x & 63;
  const float h = pa[(size_t)w * 64 + lane] + pb[(size_t)w * 64 + lane];
  rows[(size_t)w * 64 + lane] = h;
  float s1 = h, s2 = h * h;
  #pragma unroll
  for (int off = 32; off; off >>= 1) {
    s1 += __shfl_xor(s1, off);
    s2 += __shfl_xor(s2, off);
  }
  if (lane == 0) {
    sum_out[w] = s1;
    inv_out[w] = rsqrtf(s2 - s1 * s1 * (1.0f / 64.0f));
  }
}

// ===================== K3a: dual dot tiles (p and a-update) =====================
// Per block: k fixed, 64 i x 64 b tile, reduce over d=64. LDS stored d-major
// (T[d][row], stride 68) so per-d frag reads are aligned b128, 2-way max.
// MODE 0: round 0 (no a). MODE 1: a = dot(hm,v). MODE 2: a += dot(hm,v).
template <int MODE>
__global__ __launch_bounds__(256) void k_corr(
    const float* __restrict__ hm, const float* __restrict__ vbuf,
    const float* __restrict__ y,
    const float* __restrict__ summ, const float* __restrict__ invx,
    const float* __restrict__ sy, const float* __restrict__ invy,
    float* __restrict__ a, float* __restrict__ pd)
{
  __shared__ __align__(16) float HMT[64 * 68];
  __shared__ __align__(16) float YT[64 * 68];
  __shared__ __align__(16) float VT[64 * 68];
  const int t = threadIdx.x;
  const int tx = t & 15, ty = t >> 4;
  const int b0 = blockIdx.x * 64;
  const int i0 = blockIdx.y * 64;
  const int k = blockIdx.z;

  #pragma unroll
  for (int jj = 0; jj < 4; ++jj) {
    const int id = t + jj * 256;
    const int r = id >> 4;
    const int c4 = (id & 15) << 2;
    const float4 h4 = *(const float4*)&hm[(size_t)(i0 + r) * NOUT + k * 64 + c4];
    HMT[(c4 + 0) * 68 + r] = h4.x;
    HMT[(c4 + 1) * 68 + r] = h4.y;
    HMT[(c4 + 2) * 68 + r] = h4.z;
    HMT[(c4 + 3) * 68 + r] = h4.w;
    const float4 y4 = *(const float4*)&y[((size_t)(b0 + r) * KC + k) * 64 + c4];
    YT[(c4 + 0) * 68 + r] = y4.x;
    YT[(c4 + 1) * 68 + r] = y4.y;
    YT[(c4 + 2) * 68 + r] = y4.z;
    YT[(c4 + 3) * 68 + r] = y4.w;
    if (MODE) {
      const float4 v4 = *(const float4*)&vbuf[((size_t)(b0 + r) * KC + k) * 64 + c4];
      VT[(c4 + 0) * 68 + r] = v4.x;
      VT[(c4 + 1) * 68 + r] = v4.y;
      VT[(c4 + 2) * 68 + r] = v4.z;
      VT[(c4 + 3) * 68 + r] = v4.w;
    }
  }
  __syncthreads();

  float accP[4][4] = {};
  float accA[4][4] = {};
  #pragma unroll 4
  for (int d = 0; d < 64; ++d) {
    const float4 a4 = *(const float4*)&HMT[d * 68 + ty * 4];
    const float4 y4 = *(const float4*)&YT[d * 68 + tx * 4];
    const float am[4] = {a4.x, a4.y, a4.z, a4.w};
    const float yn[4] = {y4.x, y4.y, y4.z, y4.w};
    #pragma unroll
    for (int mi = 0; mi < 4; ++mi) {
      #pragma unroll
      for (int nj = 0; nj < 4; ++nj) accP[mi][nj] += am[mi] * yn[nj];
    }
    if (MODE) {
      const float4 v4 = *(const float4*)&VT[d * 68 + tx * 4];
      const float vn[4] = {v4.x, v4.y, v4.z, v4.w};
      #pragma unroll
      for (int mi = 0; mi < 4; ++mi) {
        #pragma unroll
        for (int nj = 0; nj < 4; ++nj) accA[mi][nj] += am[mi] * vn[nj];
      }
    }
  }

  float sm[4], ix[4], syv[4], iyv[4];
  #pragma unroll
  for (int mi = 0; mi < 4; ++mi) {
    sm[mi] = summ[(size_t)(i0 + ty * 4 + mi) * KC + k];
    ix[mi] = invx[(size_t)(i0 + ty * 4 + mi) * KC + k];
  }
  #pragma unroll
  for (int nj = 0; nj < 4; ++nj) {
    syv[nj] = sy[(size_t)(b0 + tx * 4 + nj) * KC + k];
    iyv[nj] = invy[(size_t)(b0 + tx * 4 + nj) * KC + k];
  }
  #pragma unroll
  for (int nj = 0; nj < 4; ++nj) {
    const int b = b0 + tx * 4 + nj;
    const size_t base = ((size_t)(b * KC + k)) * 512 + i0 + ty * 4;
    if (MODE == 1) {
      float4 st;
      st.x = accA[0][nj]; st.y = accA[1][nj]; st.z = accA[2][nj]; st.w = accA[3][nj];
      *(float4*)&a[base] = st;
    } else if (MODE == 2) {
      float4 old = *(const float4*)&a[base];
      float4 st;
      st.x = old.x + accA[0][nj]; st.y = old.y + accA[1][nj];
      st.z = old.z + accA[2][nj]; st.w = old.w + accA[3][nj];
      *(float4*)&a[base] = st;
    }
    float4 pv;
    pv.x = tanhf((accP[0][nj] - sm[0] * syv[nj] * (1.0f / 64.0f)) * ix[0] * iyv[nj]);
    pv.y = tanhf((accP[1][nj] - sm[1] * syv[nj] * (1.0f / 64.0f)) * ix[1] * iyv[nj]);
    pv.z = tanhf((accP[2][nj] - sm[2] * syv[nj] * (1.0f / 64.0f)) * ix[2] * iyv[nj]);
    pv.w = tanhf((accP[3][nj] - sm[3] * syv[nj] * (1.0f / 64.0f)) * ix[3] * iyv[nj]);
    *(float4*)&pd[base] = pv;
  }
}

// ===================== K3b: softmax over K=16 and dsp = d - p ====================
template <int UNIFORM>
__global__ __launch_bounds__(256) void k_softmax(
    const float* __restrict__ a, float* __restrict__ pd)
{
  const int g = blockIdx.x * 256 + threadIdx.x;
  const int b = g >> 9, i = g & 511;
  const size_t base = (size_t)b * 8192 + i;
  float dv[16];
  if (UNIFORM) {
    #pragma unroll
    for (int kk = 0; kk < 16; ++kk) dv[kk] = 0.0625f;
  } else {
    float av[16];
    float mx = -1e30f;
    #pragma unroll
    for (int kk = 0; kk < 16; ++kk) {
      av[kk] = a[base + (size_t)kk * 512];
      mx = fmaxf(mx, av[kk]);
    }
    float s = 0.f;
    #pragma unroll
    for (int kk = 0; kk < 16; ++kk) { av[kk] = __expf(av[kk] - mx); s += av[kk]; }
    const float inv = 1.0f / s;
    #pragma unroll
    for (int kk = 0; kk < 16; ++kk) dv[kk] = av[kk] * inv;
  }
  #pragma unroll
  for (int kk = 0; kk < 16; ++kk) {
    const size_t idx = base + (size_t)kk * 512;
    pd[idx] = dv[kk] - pd[idx];
  }
}

// ===================== K4: hat_v reduction over i, squash, y update =============
// Block: one k, 8 consecutive b. 4 waves x 2 b per wave; lane = d.
template <int FINAL>
__global__ __launch_bounds__(256) void k_hatv(
    const float* __restrict__ hm, const float* __restrict__ dsp,
    float* __restrict__ vbuf, float* __restrict__ y,
    float* __restrict__ sy, float* __restrict__ invy, float* __restrict__ outp)
{
  __shared__ __align__(16) float sd[8][512];
  const int t = threadIdx.x;
  const int k = blockIdx.x & 15;
  const int b0 = (blockIdx.x >> 4) * 8;
  #pragma unroll
  for (int jj = 0; jj < 4; ++jj) {
    const int id = t + jj * 256;
    const int r = id >> 7;
    const int c4 = (id & 127) << 2;
    *(float4*)&sd[r][c4] =
        *(const float4*)&dsp[((size_t)((b0 + r) * KC + k)) * 512 + c4];
  }
  __syncthreads();
  const int lane = t & 63, w = t >> 6;
  const int bl0 = w * 2, bl1 = bl0 + 1;
  float acc0 = 0.f, acc1 = 0.f;
  const float* hp = hm + (size_t)k * 64 + lane;
  #pragma unroll 8
  for (int i = 0; i < 512; ++i) {
    const float h = hp[(size_t)i * 1024];
    acc0 = fmaf(h, sd[bl0][i], acc0);
    acc1 = fmaf(h, sd[bl1][i], acc1);
  }
  #pragma unroll
  for (int which = 0; which < 2; ++which) {
    const float hv = which ? acc1 : acc0;
    const int b = b0 + (which ? bl1 : bl0);
    float sq = hv * hv;
    #pragma unroll
    for (int off = 32; off; off >>= 1) sq += __shfl_xor(sq, off);
    const float vv = (sq / (1.0f + sq)) * hv * rsqrtf(sq + 1e-8f);
    if (FINAL) {
      outp[(size_t)b * NOUT + k * 64 + lane] = vv;
    } else {
      const size_t yi = ((size_t)(b * KC + k)) * 64 + lane;
      vbuf[yi] = vv;
      const float yn = (y[yi] + vv) * 0.5f;
      y[yi] = yn;
      float s1 = yn, s2 = yn * yn;
      #pragma unroll
      for (int off = 32; off; off >>= 1) {
        s1 += __shfl_xor(s1, off);
        s2 += __shfl_xor(s2, off);
      }
      if (lane == 0) {
        sy[b * KC + k] = s1;
        invy[b * KC + k] = rsqrtf(s2 - s1 * s1 * (1.0f / 64.0f));
      }
    }
  }
}

// ===================== launch =====================
extern "C" void kernel_launch(void* const* d_in, const int* in_sizes, int n_in,
                              void* d_out, int out_size, void* d_ws, size_t ws_size,
                              hipStream_t stream) {
  const float* m  = (const float*)d_in[0];
  const float* q  = (const float*)d_in[1];
  const float* Ww = (const float*)d_in[2];
  const float* Wb = (const float*)d_in[3];
  float* ws = (float*)d_ws;

  float* p0    = ws + OFF_P0;
  float* p1    = ws + OFF_P1;
  float* aB    = ws + OFF_A;
  float* pdB   = ws + OFF_PD;
  float* hmB   = ws + OFF_HM;
  float* yB    = ws + OFF_Y;
  float* vB    = ws + OFF_V;
  float* summB = ws + OFF_SUMM;
  float* invxB = ws + OFF_INVX;
  float* syB   = ws + OFF_SY;
  float* invyB = ws + OFF_INVY;
  float* outp  = (float*)d_out;

  // GEMMs (split-K=2) for hat_m (rows 0..511) and hat_q (rows 512..639)
  k_gemm<<<dim3(16, 10, 2), 256, 0, stream>>>(m, q, Ww, Wb, p0, p1);
  // sum parts + stats
  k_rowstats<<<2048, 256, 0, stream>>>(p0, p1, hmB, summB, invxB);
  k_rowstats<<<512, 256, 0, stream>>>(p0 + (size_t)IC * NOUT, p1 + (size_t)IC * NOUT,
                                      yB, syB, invyB);
  // round 0
  k_corr<0><<<dim3(2, 8, 16), 256, 0, stream>>>(hmB, vB, yB, summB, invxB, syB, invyB, aB, pdB);
  k_softmax<1><<<256, 256, 0, stream>>>(aB, pdB);
  k_hatv<0><<<256, 256, 0, stream>>>(hmB, pdB, vB, yB, syB, invyB, nullptr);
  // round 1
  k_corr<1><<<dim3(2, 8, 16), 256, 0, stream>>>(hmB, vB, yB, summB, invxB, syB, invyB, aB, pdB);
  k_softmax<0><<<256, 256, 0, stream>>>(aB, pdB);
  k_hatv<0><<<256, 256, 0, stream>>>(hmB, pdB, vB, yB, syB, invyB, nullptr);
  // round 2 (final)
  k_corr<2><<<dim3(2, 8, 16), 256, 0, stream>>>(hmB, vB, yB, summB, invxB, syB, invyB, aB, pdB);
  k_softmax<0><<<256, 256, 0, stream>>>(aB, pdB);
  k_hatv<1><<<256, 256, 0, stream>>>(hmB, pdB, vB, yB, syB, invyB, outp);
}

// Round 2
// 129.067 us; speedup vs baseline: 1.0929x; 1.0929x over previous
//
#include <hip/hip_runtime.h>
#include <hip/hip_bf16.h>
#include <cstdint>
#include <cstddef>

#define IC 512     // in_caps
#define IDM 768    // in_dim
#define KC 16      // num_caps
#define DC 64      // dim_caps
#define NB 128     // batch
#define NOUT 1024  // KC*DC

typedef __attribute__((ext_vector_type(8))) short short8v;
typedef __attribute__((ext_vector_type(4))) float f32x4;

static __device__ __forceinline__ ushort bf_hi(float x) {
  __hip_bfloat16 h = __float2bfloat16(x);
  return *reinterpret_cast<ushort*>(&h);
}
static __device__ __forceinline__ float bf_f(ushort u) {
  union { float f; unsigned int i; } z; z.i = ((unsigned int)u) << 16; return z.f;
}

// ===================== K0: convert m,q,Ww to bf16 hi/lo splits =====================
// A = [m;q] rows 0..639 of [640][768]; B = Ww [1024][768]. Row-major, k-contig.
__global__ __launch_bounds__(256) void k_cvt(
    const float* __restrict__ m, const float* __restrict__ q, const float* __restrict__ Ww,
    ushort* __restrict__ Ah, ushort* __restrict__ Al,
    ushort* __restrict__ Bh, ushort* __restrict__ Bl)
{
  const int gid = blockIdx.x * 256 + threadIdx.x;   // one float4 per thread
  const int NA4 = (640 * 768) / 4;                  // 122880
  const float* src; ushort* dh; ushort* dl;
  if (gid < NA4) {
    const int e = gid * 4;
    src = (e < IC * IDM) ? (m + e) : (q + (e - IC * IDM));
    dh = Ah + e; dl = Al + e;
  } else {
    const int e = (gid - NA4) * 4;
    src = Ww + e; dh = Bh + e; dl = Bl + e;
  }
  const float4 x = *(const float4*)src;
  ushort4 hv, lv;
  hv.x = bf_hi(x.x); lv.x = bf_hi(x.x - bf_f(hv.x));
  hv.y = bf_hi(x.y); lv.y = bf_hi(x.y - bf_f(hv.y));
  hv.z = bf_hi(x.z); lv.z = bf_hi(x.z - bf_f(hv.z));
  hv.w = bf_hi(x.w); lv.w = bf_hi(x.w - bf_f(hv.w));
  *(ushort4*)dh = hv;
  *(ushort4*)dl = lv;
}

// ===================== K1: MFMA GEMM C=[A]@[B^T]+bias, fused row-stats ============
// 64x64 tile, 4 waves (2x2), each wave 32x32 via 2x2 16x16x32 bf16 frags.
// hi/lo split: acc += Ah*Bh + Ah*Bl + Al*Bh. Operands loaded straight from
// global (L2-resident); no LDS staging. Epilogue: bias, C store, per-(row,caps)
// sum & rsqrt(sumsq - sum^2/64).
__global__ __launch_bounds__(256) void k_gemm_mfma(
    const ushort* __restrict__ Ah, const ushort* __restrict__ Al,
    const ushort* __restrict__ Bh, const ushort* __restrict__ Bl,
    const float* __restrict__ Wb,
    float* __restrict__ C,            // [640][1024]; rows 512.. are y
    float* __restrict__ summ, float* __restrict__ invx,
    float* __restrict__ sy, float* __restrict__ invy)
{
  __shared__ float lds_s[2][2][64];   // [wc][sum|sq][row_local]
  const int t = threadIdx.x;
  const int w = t >> 6, L = t & 63;
  const int wr = w >> 1, wc = w & 1;
  const int g = L >> 4, c = L & 15;
  const int n0 = blockIdx.x * 64;
  const int r0 = blockIdx.y * 64;

  const int arow = r0 + wr * 32 + c;   // + mi*16
  const int bcol = n0 + wc * 32 + c;   // + ni*16
  const int kfrag = g * 8;

  const ushort* pAh = Ah + (size_t)arow * IDM + kfrag;
  const ushort* pAl = Al + (size_t)arow * IDM + kfrag;
  const ushort* pBh = Bh + (size_t)bcol * IDM + kfrag;
  const ushort* pBl = Bl + (size_t)bcol * IDM + kfrag;

  f32x4 acc00 = {}, acc01 = {}, acc10 = {}, acc11 = {};
  #pragma unroll 4
  for (int kb = 0; kb < IDM; kb += 32) {
    const short8v ah0 = *(const short8v*)(pAh + kb);
    const short8v ah1 = *(const short8v*)(pAh + 16 * IDM + kb);
    const short8v al0 = *(const short8v*)(pAl + kb);
    const short8v al1 = *(const short8v*)(pAl + 16 * IDM + kb);
    const short8v bh0 = *(const short8v*)(pBh + kb);
    const short8v bh1 = *(const short8v*)(pBh + 16 * IDM + kb);
    const short8v bl0 = *(const short8v*)(pBl + kb);
    const short8v bl1 = *(const short8v*)(pBl + 16 * IDM + kb);
    acc00 = __builtin_amdgcn_mfma_f32_16x16x32_bf16(ah0, bh0, acc00, 0, 0, 0);
    acc01 = __builtin_amdgcn_mfma_f32_16x16x32_bf16(ah0, bh1, acc01, 0, 0, 0);
    acc10 = __builtin_amdgcn_mfma_f32_16x16x32_bf16(ah1, bh0, acc10, 0, 0, 0);
    acc11 = __builtin_amdgcn_mfma_f32_16x16x32_bf16(ah1, bh1, acc11, 0, 0, 0);
    acc00 = __builtin_amdgcn_mfma_f32_16x16x32_bf16(ah0, bl0, acc00, 0, 0, 0);
    acc00 = __builtin_amdgcn_mfma_f32_16x16x32_bf16(al0, bh0, acc00, 0, 0, 0);
    acc01 = __builtin_amdgcn_mfma_f32_16x16x32_bf16(ah0, bl1, acc01, 0, 0, 0);
    acc01 = __builtin_amdgcn_mfma_f32_16x16x32_bf16(al0, bh1, acc01, 0, 0, 0);
    acc10 = __builtin_amdgcn_mfma_f32_16x16x32_bf16(ah1, bl0, acc10, 0, 0, 0);
    acc10 = __builtin_amdgcn_mfma_f32_16x16x32_bf16(al1, bh0, acc10, 0, 0, 0);
    acc11 = __builtin_amdgcn_mfma_f32_16x16x32_bf16(ah1, bl1, acc11, 0, 0, 0);
    acc11 = __builtin_amdgcn_mfma_f32_16x16x32_bf16(al1, bh1, acc11, 0, 0, 0);
  }

  const float bias0 = Wb[bcol];
  const float bias1 = Wb[bcol + 16];

  #pragma unroll
  for (int mi = 0; mi < 2; ++mi) {
    const f32x4 a0 = mi ? acc10 : acc00;
    const f32x4 a1 = mi ? acc11 : acc01;
    #pragma unroll
    for (int j = 0; j < 4; ++j) {
      const float v0 = a0[j] + bias0;
      const float v1 = a1[j] + bias1;
      const int row_l = wr * 32 + mi * 16 + 4 * g + j;
      const int row = r0 + row_l;
      C[(size_t)row * NOUT + bcol] = v0;
      C[(size_t)row * NOUT + bcol + 16] = v1;
      float s = v0 + v1;
      float q2 = v0 * v0 + v1 * v1;
      #pragma unroll
      for (int off = 1; off < 16; off <<= 1) {
        s += __shfl_xor(s, off);
        q2 += __shfl_xor(q2, off);
      }
      if (c == 0) {
        lds_s[wc][0][row_l] = s;
        lds_s[wc][1][row_l] = q2;
      }
    }
  }
  __syncthreads();
  if (t < 64) {
    const int row_l = t;
    const int row = r0 + row_l;
    const float s = lds_s[0][0][row_l] + lds_s[1][0][row_l];
    const float q2 = lds_s[0][1][row_l] + lds_s[1][1][row_l];
    const float inv = rsqrtf(q2 - s * s * (1.0f / 64.0f));
    const int k = n0 >> 6;
    if (row < IC) {
      summ[row * KC + k] = s;
      invx[row * KC + k] = inv;
    } else {
      sy[(row - IC) * KC + k] = s;
      invy[(row - IC) * KC + k] = inv;
    }
  }
}

// ===================== K3a: dual dot tiles (p and a-update) =====================
// Per block: k fixed, 64 i x 64 b tile, reduce over d=64. LDS stored d-major.
// MODE 0: round 0 (no a). MODE 1: a = dot(hm,v). MODE 2: a += dot(hm,v).
template <int MODE>
__global__ __launch_bounds__(256) void k_corr(
    const float* __restrict__ hm, const float* __restrict__ vbuf,
    const float* __restrict__ y,
    const float* __restrict__ summ, const float* __restrict__ invx,
    const float* __restrict__ sy, const float* __restrict__ invy,
    float* __restrict__ a, float* __restrict__ pd)
{
  __shared__ __align__(16) float HMT[64 * 68];
  __shared__ __align__(16) float YT[64 * 68];
  __shared__ __align__(16) float VT[64 * 68];
  const int t = threadIdx.x;
  const int tx = t & 15, ty = t >> 4;
  const int b0 = blockIdx.x * 64;
  const int i0 = blockIdx.y * 64;
  const int k = blockIdx.z;

  #pragma unroll
  for (int jj = 0; jj < 4; ++jj) {
    const int id = t + jj * 256;
    const int r = id >> 4;
    const int c4 = (id & 15) << 2;
    const float4 h4 = *(const float4*)&hm[(size_t)(i0 + r) * NOUT + k * 64 + c4];
    HMT[(c4 + 0) * 68 + r] = h4.x;
    HMT[(c4 + 1) * 68 + r] = h4.y;
    HMT[(c4 + 2) * 68 + r] = h4.z;
    HMT[(c4 + 3) * 68 + r] = h4.w;
    const float4 y4 = *(const float4*)&y[((size_t)(b0 + r) * KC + k) * 64 + c4];
    YT[(c4 + 0) * 68 + r] = y4.x;
    YT[(c4 + 1) * 68 + r] = y4.y;
    YT[(c4 + 2) * 68 + r] = y4.z;
    YT[(c4 + 3) * 68 + r] = y4.w;
    if (MODE) {
      const float4 v4 = *(const float4*)&vbuf[((size_t)(b0 + r) * KC + k) * 64 + c4];
      VT[(c4 + 0) * 68 + r] = v4.x;
      VT[(c4 + 1) * 68 + r] = v4.y;
      VT[(c4 + 2) * 68 + r] = v4.z;
      VT[(c4 + 3) * 68 + r] = v4.w;
    }
  }
  __syncthreads();

  float accP[4][4] = {};
  float accA[4][4] = {};
  #pragma unroll 4
  for (int d = 0; d < 64; ++d) {
    const float4 a4 = *(const float4*)&HMT[d * 68 + ty * 4];
    const float4 y4 = *(const float4*)&YT[d * 68 + tx * 4];
    const float am[4] = {a4.x, a4.y, a4.z, a4.w};
    const float yn[4] = {y4.x, y4.y, y4.z, y4.w};
    #pragma unroll
    for (int mi = 0; mi < 4; ++mi) {
      #pragma unroll
      for (int nj = 0; nj < 4; ++nj) accP[mi][nj] += am[mi] * yn[nj];
    }
    if (MODE) {
      const float4 v4 = *(const float4*)&VT[d * 68 + tx * 4];
      const float vn[4] = {v4.x, v4.y, v4.z, v4.w};
      #pragma unroll
      for (int mi = 0; mi < 4; ++mi) {
        #pragma unroll
        for (int nj = 0; nj < 4; ++nj) accA[mi][nj] += am[mi] * vn[nj];
      }
    }
  }

  float sm[4], ix[4], syv[4], iyv[4];
  #pragma unroll
  for (int mi = 0; mi < 4; ++mi) {
    sm[mi] = summ[(size_t)(i0 + ty * 4 + mi) * KC + k];
    ix[mi] = invx[(size_t)(i0 + ty * 4 + mi) * KC + k];
  }
  #pragma unroll
  for (int nj = 0; nj < 4; ++nj) {
    syv[nj] = sy[(size_t)(b0 + tx * 4 + nj) * KC + k];
    iyv[nj] = invy[(size_t)(b0 + tx * 4 + nj) * KC + k];
  }
  #pragma unroll
  for (int nj = 0; nj < 4; ++nj) {
    const int b = b0 + tx * 4 + nj;
    const size_t base = ((size_t)(b * KC + k)) * 512 + i0 + ty * 4;
    if (MODE == 1) {
      float4 st;
      st.x = accA[0][nj]; st.y = accA[1][nj]; st.z = accA[2][nj]; st.w = accA[3][nj];
      *(float4*)&a[base] = st;
    } else if (MODE == 2) {
      float4 old = *(const float4*)&a[base];
      float4 st;
      st.x = old.x + accA[0][nj]; st.y = old.y + accA[1][nj];
      st.z = old.z + accA[2][nj]; st.w = old.w + accA[3][nj];
      *(float4*)&a[base] = st;
    }
    float4 pv;
    pv.x = tanhf((accP[0][nj] - sm[0] * syv[nj] * (1.0f / 64.0f)) * ix[0] * iyv[nj]);
    pv.y = tanhf((accP[1][nj] - sm[1] * syv[nj] * (1.0f / 64.0f)) * ix[1] * iyv[nj]);
    pv.z = tanhf((accP[2][nj] - sm[2] * syv[nj] * (1.0f / 64.0f)) * ix[2] * iyv[nj]);
    pv.w = tanhf((accP[3][nj] - sm[3] * syv[nj] * (1.0f / 64.0f)) * ix[3] * iyv[nj]);
    *(float4*)&pd[base] = pv;
  }
}

// ===================== K3b: softmax over K=16 and dsp = d - p ====================
template <int UNIFORM>
__global__ __launch_bounds__(256) void k_softmax(
    const float* __restrict__ a, float* __restrict__ pd)
{
  const int g = blockIdx.x * 256 + threadIdx.x;
  const int b = g >> 9, i = g & 511;
  const size_t base = (size_t)b * 8192 + i;
  float dv[16];
  if (UNIFORM) {
    #pragma unroll
    for (int kk = 0; kk < 16; ++kk) dv[kk] = 0.0625f;
  } else {
    float av[16];
    float mx = -1e30f;
    #pragma unroll
    for (int kk = 0; kk < 16; ++kk) {
      av[kk] = a[base + (size_t)kk * 512];
      mx = fmaxf(mx, av[kk]);
    }
    float s = 0.f;
    #pragma unroll
    for (int kk = 0; kk < 16; ++kk) { av[kk] = __expf(av[kk] - mx); s += av[kk]; }
    const float inv = 1.0f / s;
    #pragma unroll
    for (int kk = 0; kk < 16; ++kk) dv[kk] = av[kk] * inv;
  }
  #pragma unroll
  for (int kk = 0; kk < 16; ++kk) {
    const size_t idx = base + (size_t)kk * 512;
    pd[idx] = dv[kk] - pd[idx];
  }
}

// ===================== K4: hat_v reduction over i, squash, y update =============
template <int FINAL>
__global__ __launch_bounds__(256) void k_hatv(
    const float* __restrict__ hm, const float* __restrict__ dsp,
    float* __restrict__ vbuf, float* __restrict__ y,
    float* __restrict__ sy, float* __restrict__ invy, float* __restrict__ outp)
{
  __shared__ __align__(16) float sd[8][512];
  const int t = threadIdx.x;
  const int k = blockIdx.x & 15;
  const int b0 = (blockIdx.x >> 4) * 8;
  #pragma unroll
  for (int jj = 0; jj < 4; ++jj) {
    const int id = t + jj * 256;
    const int r = id >> 7;
    const int c4 = (id & 127) << 2;
    *(float4*)&sd[r][c4] =
        *(const float4*)&dsp[((size_t)((b0 + r) * KC + k)) * 512 + c4];
  }
  __syncthreads();
  const int lane = t & 63, w = t >> 6;
  const int bl0 = w * 2, bl1 = bl0 + 1;
  float acc0 = 0.f, acc1 = 0.f;
  const float* hp = hm + (size_t)k * 64 + lane;
  #pragma unroll 8
  for (int i = 0; i < 512; ++i) {
    const float h = hp[(size_t)i * 1024];
    acc0 = fmaf(h, sd[bl0][i], acc0);
    acc1 = fmaf(h, sd[bl1][i], acc1);
  }
  #pragma unroll
  for (int which = 0; which < 2; ++which) {
    const float hv = which ? acc1 : acc0;
    const int b = b0 + (which ? bl1 : bl0);
    float sq = hv * hv;
    #pragma unroll
    for (int off = 32; off; off >>= 1) sq += __shfl_xor(sq, off);
    const float vv = (sq / (1.0f + sq)) * hv * rsqrtf(sq + 1e-8f);
    if (FINAL) {
      outp[(size_t)b * NOUT + k * 64 + lane] = vv;
    } else {
      const size_t yi = ((size_t)(b * KC + k)) * 64 + lane;
      vbuf[yi] = vv;
      const float yn = (y[yi] + vv) * 0.5f;
      y[yi] = yn;
      float s1 = yn, s2 = yn * yn;
      #pragma unroll
      for (int off = 32; off; off >>= 1) {
        s1 += __shfl_xor(s1, off);
        s2 += __shfl_xor(s2, off);
      }
      if (lane == 0) {
        sy[b * KC + k] = s1;
        invy[b * KC + k] = rsqrtf(s2 - s1 * s1 * (1.0f / 64.0f));
      }
    }
  }
}

// ===================== launch =====================
extern "C" void kernel_launch(void* const* d_in, const int* in_sizes, int n_in,
                              void* d_out, int out_size, void* d_ws, size_t ws_size,
                              hipStream_t stream) {
  const float* m  = (const float*)d_in[0];
  const float* q  = (const float*)d_in[1];
  const float* Ww = (const float*)d_in[2];
  const float* Wb = (const float*)d_in[3];
  char* w = (char*)d_ws;

  ushort* Ah   = (ushort*)(w + 0);          // 640*768*2  = 983040
  ushort* Al   = (ushort*)(w + 983040);
  ushort* Bh   = (ushort*)(w + 1966080);    // 1024*768*2 = 1572864
  ushort* Bl   = (ushort*)(w + 3538944);
  float*  C    = (float*)(w + 5111808);     // 640*1024*4 = 2621440 (hm rows 0..511, y rows 512..639)
  float*  hmB  = C;
  float*  yB   = C + (size_t)IC * NOUT;
  float*  vB   = (float*)(w + 7733248);     // 128*1024*4 = 524288
  float*  aB   = (float*)(w + 8257536);     // 128*16*512*4 = 4194304
  float*  pdB  = (float*)(w + 12451840);    // 4194304
  float*  summB= (float*)(w + 16646144);    // 512*16*4 = 32768
  float*  invxB= (float*)(w + 16678912);    // 32768
  float*  syB  = (float*)(w + 16711680);    // 128*16*4 = 8192
  float*  invyB= (float*)(w + 16719872);    // 8192
  float*  outp = (float*)d_out;

  k_cvt<<<1248, 256, 0, stream>>>(m, q, Ww, Ah, Al, Bh, Bl);
  k_gemm_mfma<<<dim3(16, 10), 256, 0, stream>>>(Ah, Al, Bh, Bl, Wb, C,
                                                summB, invxB, syB, invyB);
  // round 0
  k_corr<0><<<dim3(2, 8, 16), 256, 0, stream>>>(hmB, vB, yB, summB, invxB, syB, invyB, aB, pdB);
  k_softmax<1><<<256, 256, 0, stream>>>(aB, pdB);
  k_hatv<0><<<256, 256, 0, stream>>>(hmB, pdB, vB, yB, syB, invyB, nullptr);
  // round 1
  k_corr<1><<<dim3(2, 8, 16), 256, 0, stream>>>(hmB, vB, yB, summB, invxB, syB, invyB, aB, pdB);
  k_softmax<0><<<256, 256, 0, stream>>>(aB, pdB);
  k_hatv<0><<<256, 256, 0, stream>>>(hmB, pdB, vB, yB, syB, invyB, nullptr);
  // round 2 (final)
  k_corr<2><<<dim3(2, 8, 16), 256, 0, stream>>>(hmB, vB, yB, summB, invxB, syB, invyB, aB, pdB);
  k_softmax<0><<<256, 256, 0, stream>>>(aB, pdB);
  k_hatv<1><<<256, 256, 0, stream>>>(hmB, pdB, vB, yB, syB, invyB, outp);
}

// Round 3
// 106.832 us; speedup vs baseline: 1.3204x; 1.2081x over previous
//
#include <hip/hip_runtime.h>
#include <hip/hip_bf16.h>
#include <cstdint>
#include <cstddef>

#define IC 512     // in_caps
#define IDM 768    // in_dim
#define KC 16      // num_caps
#define NB 128     // batch
#define NOUT 1024  // KC*DC

typedef __attribute__((ext_vector_type(8))) short short8v;
typedef __attribute__((ext_vector_type(4))) float f32x4;

static __device__ __forceinline__ ushort bf_hi(float x) {
  __hip_bfloat16 h = __float2bfloat16(x);
  return *reinterpret_cast<ushort*>(&h);
}
static __device__ __forceinline__ float bf_f(ushort u) {
  union { float f; unsigned u32; } z; z.u32 = ((unsigned)u) << 16; return z.f;
}
static __device__ __forceinline__ void split2(float x, ushort& h, ushort& l) {
  h = bf_hi(x); l = bf_hi(x - bf_f(h));
}

// ===================== K0: convert m,q,Ww to bf16 hi/lo =====================
__global__ __launch_bounds__(256) void k_cvt(
    const float* __restrict__ m, const float* __restrict__ q, const float* __restrict__ Ww,
    ushort* __restrict__ Ah, ushort* __restrict__ Al,
    ushort* __restrict__ Bh, ushort* __restrict__ Bl)
{
  const int gid = blockIdx.x * 256 + threadIdx.x;
  const int NA4 = (640 * 768) / 4;
  const float* src; ushort* dh; ushort* dl;
  if (gid < NA4) {
    const int e = gid * 4;
    src = (e < IC * IDM) ? (m + e) : (q + (e - IC * IDM));
    dh = Ah + e; dl = Al + e;
  } else {
    const int e = (gid - NA4) * 4;
    src = Ww + e; dh = Bh + e; dl = Bl + e;
  }
  const float4 x = *(const float4*)src;
  ushort4 hv, lv;
  split2(x.x, hv.x, lv.x);
  split2(x.y, hv.y, lv.y);
  split2(x.z, hv.z, lv.z);
  split2(x.w, hv.w, lv.w);
  *(ushort4*)dh = hv;
  *(ushort4*)dl = lv;
}

// ===================== K1: MFMA GEMM + epilogue (hm/hmT/y bf16 splits, stats) ====
__global__ __launch_bounds__(256) void k_gemm_mfma(
    const ushort* __restrict__ Ah, const ushort* __restrict__ Al,
    const ushort* __restrict__ Bh, const ushort* __restrict__ Bl,
    const float* __restrict__ Wb,
    ushort* __restrict__ Hh, ushort* __restrict__ Hl,
    ushort* __restrict__ HTh, ushort* __restrict__ HTl,
    float* __restrict__ Yf, ushort* __restrict__ Yh, ushort* __restrict__ Yl,
    float* __restrict__ summ, float* __restrict__ invx,
    float* __restrict__ sy, float* __restrict__ invy)
{
  __shared__ float lds_s[2][2][64];   // [wc][sum|sq][row_local]
  const int t = threadIdx.x;
  const int w = t >> 6, L = t & 63;
  const int wr = w >> 1, wc = w & 1;
  const int g = L >> 4, c = L & 15;
  const int n0 = blockIdx.x * 64;
  const int r0 = blockIdx.y * 64;

  const int arow = r0 + wr * 32 + c;
  const int bcol = n0 + wc * 32 + c;
  const int kfrag = g * 8;

  const ushort* pAh = Ah + (size_t)arow * IDM + kfrag;
  const ushort* pAl = Al + (size_t)arow * IDM + kfrag;
  const ushort* pBh = Bh + (size_t)bcol * IDM + kfrag;
  const ushort* pBl = Bl + (size_t)bcol * IDM + kfrag;

  f32x4 acc00 = {}, acc01 = {}, acc10 = {}, acc11 = {};
  #pragma unroll 4
  for (int kb = 0; kb < IDM; kb += 32) {
    const short8v ah0 = *(const short8v*)(pAh + kb);
    const short8v ah1 = *(const short8v*)(pAh + 16 * IDM + kb);
    const short8v al0 = *(const short8v*)(pAl + kb);
    const short8v al1 = *(const short8v*)(pAl + 16 * IDM + kb);
    const short8v bh0 = *(const short8v*)(pBh + kb);
    const short8v bh1 = *(const short8v*)(pBh + 16 * IDM + kb);
    const short8v bl0 = *(const short8v*)(pBl + kb);
    const short8v bl1 = *(const short8v*)(pBl + 16 * IDM + kb);
    acc00 = __builtin_amdgcn_mfma_f32_16x16x32_bf16(ah0, bh0, acc00, 0, 0, 0);
    acc01 = __builtin_amdgcn_mfma_f32_16x16x32_bf16(ah0, bh1, acc01, 0, 0, 0);
    acc10 = __builtin_amdgcn_mfma_f32_16x16x32_bf16(ah1, bh0, acc10, 0, 0, 0);
    acc11 = __builtin_amdgcn_mfma_f32_16x16x32_bf16(ah1, bh1, acc11, 0, 0, 0);
    acc00 = __builtin_amdgcn_mfma_f32_16x16x32_bf16(ah0, bl0, acc00, 0, 0, 0);
    acc00 = __builtin_amdgcn_mfma_f32_16x16x32_bf16(al0, bh0, acc00, 0, 0, 0);
    acc01 = __builtin_amdgcn_mfma_f32_16x16x32_bf16(ah0, bl1, acc01, 0, 0, 0);
    acc01 = __builtin_amdgcn_mfma_f32_16x16x32_bf16(al0, bh1, acc01, 0, 0, 0);
    acc10 = __builtin_amdgcn_mfma_f32_16x16x32_bf16(ah1, bl0, acc10, 0, 0, 0);
    acc10 = __builtin_amdgcn_mfma_f32_16x16x32_bf16(al1, bh0, acc10, 0, 0, 0);
    acc11 = __builtin_amdgcn_mfma_f32_16x16x32_bf16(ah1, bl1, acc11, 0, 0, 0);
    acc11 = __builtin_amdgcn_mfma_f32_16x16x32_bf16(al1, bh1, acc11, 0, 0, 0);
  }

  const float bias0 = Wb[bcol];
  const float bias1 = Wb[bcol + 16];

  #pragma unroll
  for (int mi = 0; mi < 2; ++mi) {
    const f32x4 a0 = mi ? acc10 : acc00;
    const f32x4 a1 = mi ? acc11 : acc01;
    float v0s[4], v1s[4];
    #pragma unroll
    for (int j = 0; j < 4; ++j) { v0s[j] = a0[j] + bias0; v1s[j] = a1[j] + bias1; }
    const int rowb = r0 + wr * 32 + mi * 16 + 4 * g;   // rows rowb..rowb+3

    // per-row stats partials
    #pragma unroll
    for (int j = 0; j < 4; ++j) {
      float s = v0s[j] + v1s[j];
      float q2 = v0s[j] * v0s[j] + v1s[j] * v1s[j];
      #pragma unroll
      for (int off = 1; off < 16; off <<= 1) {
        s += __shfl_xor(s, off);
        q2 += __shfl_xor(q2, off);
      }
      if (c == 0) {
        const int row_l = wr * 32 + mi * 16 + 4 * g + j;
        lds_s[wc][0][row_l] = s;
        lds_s[wc][1][row_l] = q2;
      }
    }

    ushort h0[4], l0[4], h1[4], l1[4];
    #pragma unroll
    for (int j = 0; j < 4; ++j) { split2(v0s[j], h0[j], l0[j]); split2(v1s[j], h1[j], l1[j]); }

    if (rowb < IC) {
      #pragma unroll
      for (int j = 0; j < 4; ++j) {
        const size_t r = (size_t)(rowb + j) * NOUT;
        Hh[r + bcol] = h0[j]; Hl[r + bcol] = l0[j];
        Hh[r + bcol + 16] = h1[j]; Hl[r + bcol + 16] = l1[j];
      }
      *(ushort4*)&HTh[(size_t)bcol * 512 + rowb] = make_ushort4(h0[0], h0[1], h0[2], h0[3]);
      *(ushort4*)&HTl[(size_t)bcol * 512 + rowb] = make_ushort4(l0[0], l0[1], l0[2], l0[3]);
      *(ushort4*)&HTh[(size_t)(bcol + 16) * 512 + rowb] = make_ushort4(h1[0], h1[1], h1[2], h1[3]);
      *(ushort4*)&HTl[(size_t)(bcol + 16) * 512 + rowb] = make_ushort4(l1[0], l1[1], l1[2], l1[3]);
    } else {
      #pragma unroll
      for (int j = 0; j < 4; ++j) {
        const size_t r = (size_t)(rowb + j - IC) * NOUT;
        Yf[r + bcol] = v0s[j]; Yf[r + bcol + 16] = v1s[j];
        Yh[r + bcol] = h0[j]; Yl[r + bcol] = l0[j];
        Yh[r + bcol + 16] = h1[j]; Yl[r + bcol + 16] = l1[j];
      }
    }
  }
  __syncthreads();
  if (t < 64) {
    const int row_l = t;
    const int row = r0 + row_l;
    const float s = lds_s[0][0][row_l] + lds_s[1][0][row_l];
    const float q2 = lds_s[0][1][row_l] + lds_s[1][1][row_l];
    const float inv = rsqrtf(q2 - s * s * (1.0f / 64.0f));
    const int k = n0 >> 6;
    if (row < IC) {
      summ[row * KC + k] = s;
      invx[row * KC + k] = inv;
    } else {
      sy[(row - IC) * KC + k] = s;
      invy[(row - IC) * KC + k] = inv;
    }
  }
}

// ===================== K2: corr via MFMA (P = hm.y^T, a = hm.vsum^T) ============
// Block: (k, 64 i, 64 b); 4 waves 2x2; all operands direct from global, hi/lo.
template <int MODE>  // 0: P only; 1: P + a
__global__ __launch_bounds__(256) void k_corr(
    const ushort* __restrict__ Hh, const ushort* __restrict__ Hl,
    const ushort* __restrict__ Yh, const ushort* __restrict__ Yl,
    const ushort* __restrict__ Vh, const ushort* __restrict__ Vl,
    const float* __restrict__ summ, const float* __restrict__ invx,
    const float* __restrict__ syv, const float* __restrict__ invyv,
    float* __restrict__ a, float* __restrict__ pd)
{
  const int t = threadIdx.x;
  const int w = t >> 6, L = t & 63, c = L & 15, g = L >> 4;
  const int wr = w >> 1, wb = w & 1;
  const int k = blockIdx.z;
  const int i_t = blockIdx.y * 64 + wr * 32;
  const int b_t = blockIdx.x * 64 + wb * 32;
  const size_t kofs = (size_t)k * 64 + g * 8;

  const ushort* pA0h = Hh + (size_t)(i_t + c) * NOUT + kofs;
  const ushort* pA0l = Hl + (size_t)(i_t + c) * NOUT + kofs;
  const ushort* pB0h = Yh + (size_t)(b_t + c) * NOUT + kofs;
  const ushort* pB0l = Yl + (size_t)(b_t + c) * NOUT + kofs;
  const ushort* pV0h = Vh + (size_t)(b_t + c) * NOUT + kofs;
  const ushort* pV0l = Vl + (size_t)(b_t + c) * NOUT + kofs;

  f32x4 P00 = {}, P01 = {}, P10 = {}, P11 = {};
  f32x4 A00 = {}, A01 = {}, A10 = {}, A11 = {};
  #pragma unroll
  for (int kk = 0; kk < 64; kk += 32) {
    const short8v a0h = *(const short8v*)(pA0h + kk);
    const short8v a1h = *(const short8v*)(pA0h + 16 * NOUT + kk);
    const short8v a0l = *(const short8v*)(pA0l + kk);
    const short8v a1l = *(const short8v*)(pA0l + 16 * NOUT + kk);
    const short8v y0h = *(const short8v*)(pB0h + kk);
    const short8v y1h = *(const short8v*)(pB0h + 16 * NOUT + kk);
    const short8v y0l = *(const short8v*)(pB0l + kk);
    const short8v y1l = *(const short8v*)(pB0l + 16 * NOUT + kk);
    P00 = __builtin_amdgcn_mfma_f32_16x16x32_bf16(a0h, y0h, P00, 0, 0, 0);
    P01 = __builtin_amdgcn_mfma_f32_16x16x32_bf16(a0h, y1h, P01, 0, 0, 0);
    P10 = __builtin_amdgcn_mfma_f32_16x16x32_bf16(a1h, y0h, P10, 0, 0, 0);
    P11 = __builtin_amdgcn_mfma_f32_16x16x32_bf16(a1h, y1h, P11, 0, 0, 0);
    P00 = __builtin_amdgcn_mfma_f32_16x16x32_bf16(a0h, y0l, P00, 0, 0, 0);
    P00 = __builtin_amdgcn_mfma_f32_16x16x32_bf16(a0l, y0h, P00, 0, 0, 0);
    P01 = __builtin_amdgcn_mfma_f32_16x16x32_bf16(a0h, y1l, P01, 0, 0, 0);
    P01 = __builtin_amdgcn_mfma_f32_16x16x32_bf16(a0l, y1h, P01, 0, 0, 0);
    P10 = __builtin_amdgcn_mfma_f32_16x16x32_bf16(a1h, y0l, P10, 0, 0, 0);
    P10 = __builtin_amdgcn_mfma_f32_16x16x32_bf16(a1l, y0h, P10, 0, 0, 0);
    P11 = __builtin_amdgcn_mfma_f32_16x16x32_bf16(a1h, y1l, P11, 0, 0, 0);
    P11 = __builtin_amdgcn_mfma_f32_16x16x32_bf16(a1l, y1h, P11, 0, 0, 0);
    if (MODE) {
      const short8v v0h = *(const short8v*)(pV0h + kk);
      const short8v v1h = *(const short8v*)(pV0h + 16 * NOUT + kk);
      const short8v v0l = *(const short8v*)(pV0l + kk);
      const short8v v1l = *(const short8v*)(pV0l + 16 * NOUT + kk);
      A00 = __builtin_amdgcn_mfma_f32_16x16x32_bf16(a0h, v0h, A00, 0, 0, 0);
      A01 = __builtin_amdgcn_mfma_f32_16x16x32_bf16(a0h, v1h, A01, 0, 0, 0);
      A10 = __builtin_amdgcn_mfma_f32_16x16x32_bf16(a1h, v0h, A10, 0, 0, 0);
      A11 = __builtin_amdgcn_mfma_f32_16x16x32_bf16(a1h, v1h, A11, 0, 0, 0);
      A00 = __builtin_amdgcn_mfma_f32_16x16x32_bf16(a0h, v0l, A00, 0, 0, 0);
      A00 = __builtin_amdgcn_mfma_f32_16x16x32_bf16(a0l, v0h, A00, 0, 0, 0);
      A01 = __builtin_amdgcn_mfma_f32_16x16x32_bf16(a0h, v1l, A01, 0, 0, 0);
      A01 = __builtin_amdgcn_mfma_f32_16x16x32_bf16(a0l, v1h, A01, 0, 0, 0);
      A10 = __builtin_amdgcn_mfma_f32_16x16x32_bf16(a1h, v0l, A10, 0, 0, 0);
      A10 = __builtin_amdgcn_mfma_f32_16x16x32_bf16(a1l, v0h, A10, 0, 0, 0);
      A11 = __builtin_amdgcn_mfma_f32_16x16x32_bf16(a1h, v1l, A11, 0, 0, 0);
      A11 = __builtin_amdgcn_mfma_f32_16x16x32_bf16(a1l, v1h, A11, 0, 0, 0);
    }
  }

  float sm[2][4], ix[2][4];
  #pragma unroll
  for (int mi = 0; mi < 2; ++mi)
    #pragma unroll
    for (int j = 0; j < 4; ++j) {
      const int i = i_t + mi * 16 + 4 * g + j;
      sm[mi][j] = summ[i * KC + k];
      ix[mi][j] = invx[i * KC + k];
    }
  float syc[2], iyc[2];
  #pragma unroll
  for (int nj = 0; nj < 2; ++nj) {
    const int b = b_t + nj * 16 + c;
    syc[nj] = syv[b * KC + k];
    iyc[nj] = invyv[b * KC + k];
  }

  #pragma unroll
  for (int mi = 0; mi < 2; ++mi) {
    #pragma unroll
    for (int nj = 0; nj < 2; ++nj) {
      const f32x4 Pf = (mi == 0) ? (nj == 0 ? P00 : P01) : (nj == 0 ? P10 : P11);
      f32x4 o;
      #pragma unroll
      for (int j = 0; j < 4; ++j)
        o[j] = tanhf((Pf[j] - sm[mi][j] * syc[nj] * (1.0f / 64.0f)) * ix[mi][j] * iyc[nj]);
      const size_t base = (size_t)(b_t + nj * 16 + c) * 8192 + (size_t)k * 512
                        + i_t + mi * 16 + 4 * g;
      *(f32x4*)&pd[base] = o;
      if (MODE) {
        const f32x4 Af = (mi == 0) ? (nj == 0 ? A00 : A01) : (nj == 0 ? A10 : A11);
        *(f32x4*)&a[base] = Af;
      }
    }
  }
}

// ===================== K3: softmax over K=16, dsp = d - p -> bf16 h/l ============
template <int UNIFORM>
__global__ __launch_bounds__(256) void k_softmax(
    const float* __restrict__ a, const float* __restrict__ pd,
    ushort* __restrict__ Dh, ushort* __restrict__ Dl)
{
  const int gid = blockIdx.x * 256 + threadIdx.x;
  const int b = gid >> 9, i = gid & 511;
  const size_t base = (size_t)b * 8192 + i;
  float dv[16];
  if (UNIFORM) {
    #pragma unroll
    for (int kk = 0; kk < 16; ++kk) dv[kk] = 0.0625f;
  } else {
    float av[16];
    float mx = -1e30f;
    #pragma unroll
    for (int kk = 0; kk < 16; ++kk) {
      av[kk] = a[base + (size_t)kk * 512];
      mx = fmaxf(mx, av[kk]);
    }
    float s = 0.f;
    #pragma unroll
    for (int kk = 0; kk < 16; ++kk) { av[kk] = __expf(av[kk] - mx); s += av[kk]; }
    const float inv = 1.0f / s;
    #pragma unroll
    for (int kk = 0; kk < 16; ++kk) dv[kk] = av[kk] * inv;
  }
  #pragma unroll
  for (int kk = 0; kk < 16; ++kk) {
    const size_t idx = base + (size_t)kk * 512;
    const float x = dv[kk] - pd[idx];
    ushort h, l;
    split2(x, h, l);
    Dh[idx] = h; Dl[idx] = l;
  }
}

// ===================== K4: hat_v via MFMA + squash + y/vsum update ==============
// Block: (k, 16 b); 4 waves, wave w covers d = w*16..w*16+15, K = i = 512.
template <int ROUND>  // 0: vsum=v + y-upd; 1: vsum+=v + y-upd; 2: final out only
__global__ __launch_bounds__(256) void k_hatv(
    const ushort* __restrict__ Dh, const ushort* __restrict__ Dl,
    const ushort* __restrict__ HTh, const ushort* __restrict__ HTl,
    float* __restrict__ Vf, ushort* __restrict__ Vh, ushort* __restrict__ Vl,
    float* __restrict__ Yf, ushort* __restrict__ Yh, ushort* __restrict__ Yl,
    float* __restrict__ syv, float* __restrict__ invyv, float* __restrict__ outp)
{
  const int t = threadIdx.x;
  const int w = t >> 6, L = t & 63, c = L & 15, g = L >> 4;
  const int k = blockIdx.x & 15;
  const int b0 = (blockIdx.x >> 4) * 16;

  const ushort* pAh = Dh + (size_t)(b0 + c) * 8192 + (size_t)k * 512 + g * 8;
  const ushort* pAl = Dl + (size_t)(b0 + c) * 8192 + (size_t)k * 512 + g * 8;
  const ushort* pBh = HTh + (size_t)(k * 64 + w * 16 + c) * 512 + g * 8;
  const ushort* pBl = HTl + (size_t)(k * 64 + w * 16 + c) * 512 + g * 8;

  f32x4 acc = {};
  #pragma unroll 4
  for (int i = 0; i < 512; i += 32) {
    const short8v ah = *(const short8v*)(pAh + i);
    const short8v al = *(const short8v*)(pAl + i);
    const short8v bh = *(const short8v*)(pBh + i);
    const short8v bl = *(const short8v*)(pBl + i);
    acc = __builtin_amdgcn_mfma_f32_16x16x32_bf16(ah, bh, acc, 0, 0, 0);
    acc = __builtin_amdgcn_mfma_f32_16x16x32_bf16(ah, bl, acc, 0, 0, 0);
    acc = __builtin_amdgcn_mfma_f32_16x16x32_bf16(al, bh, acc, 0, 0, 0);
  }

  __shared__ float red[3][4][16];
  __shared__ float sscale[16];
  float sq[4];
  #pragma unroll
  for (int j = 0; j < 4; ++j) {
    sq[j] = acc[j] * acc[j];
    #pragma unroll
    for (int off = 1; off < 16; off <<= 1) sq[j] += __shfl_xor(sq[j], off);
  }
  if (c == 0) {
    #pragma unroll
    for (int j = 0; j < 4; ++j) red[0][w][4 * g + j] = sq[j];
  }
  __syncthreads();
  if (t < 16) {
    const float s = red[0][0][t] + red[0][1][t] + red[0][2][t] + red[0][3][t];
    sscale[t] = (s / (1.0f + s)) * rsqrtf(s + 1e-8f);
  }
  __syncthreads();

  const int d = w * 16 + c;
  float s1[4], s2[4];
  #pragma unroll
  for (int j = 0; j < 4; ++j) {
    const int bl_ = 4 * g + j;
    const int b = b0 + bl_;
    const float v = acc[j] * sscale[bl_];
    const size_t idx = (size_t)b * NOUT + (size_t)k * 64 + d;
    if (ROUND == 2) {
      outp[idx] = v;
    } else {
      const float vs = (ROUND == 0) ? v : (Vf[idx] + v);
      Vf[idx] = vs;
      ushort h, l2;
      split2(vs, h, l2); Vh[idx] = h; Vl[idx] = l2;
      const float yn = (Yf[idx] + v) * 0.5f;
      Yf[idx] = yn;
      split2(yn, h, l2); Yh[idx] = h; Yl[idx] = l2;
      s1[j] = yn; s2[j] = yn * yn;
    }
  }
  if (ROUND != 2) {
    #pragma unroll
    for (int j = 0; j < 4; ++j) {
      #pragma unroll
      for (int off = 1; off < 16; off <<= 1) {
        s1[j] += __shfl_xor(s1[j], off);
        s2[j] += __shfl_xor(s2[j], off);
      }
    }
    if (c == 0) {
      #pragma unroll
      for (int j = 0; j < 4; ++j) {
        red[1][w][4 * g + j] = s1[j];
        red[2][w][4 * g + j] = s2[j];
      }
    }
    __syncthreads();
    if (t < 16) {
      const float s = red[1][0][t] + red[1][1][t] + red[1][2][t] + red[1][3][t];
      const float q2 = red[2][0][t] + red[2][1][t] + red[2][2][t] + red[2][3][t];
      syv[(b0 + t) * KC + k] = s;
      invyv[(b0 + t) * KC + k] = rsqrtf(q2 - s * s * (1.0f / 64.0f));
    }
  }
}

// ===================== launch =====================
extern "C" void kernel_launch(void* const* d_in, const int* in_sizes, int n_in,
                              void* d_out, int out_size, void* d_ws, size_t ws_size,
                              hipStream_t stream) {
  const float* m  = (const float*)d_in[0];
  const float* q  = (const float*)d_in[1];
  const float* Ww = (const float*)d_in[2];
  const float* Wb = (const float*)d_in[3];
  char* w = (char*)d_ws;

  ushort* Ah   = (ushort*)(w + 0);          //  640* 768*2 =  983040
  ushort* Al   = (ushort*)(w + 983040);
  ushort* Bh   = (ushort*)(w + 1966080);    // 1024* 768*2 = 1572864
  ushort* Bl   = (ushort*)(w + 3538944);
  ushort* Hh   = (ushort*)(w + 5111808);    //  512*1024*2 = 1048576
  ushort* Hl   = (ushort*)(w + 6160384);
  ushort* HTh  = (ushort*)(w + 7208960);    // 1024* 512*2 = 1048576
  ushort* HTl  = (ushort*)(w + 8257536);
  float*  Yf   = (float*)(w + 9306112);     //  128*1024*4 =  524288
  ushort* Yh   = (ushort*)(w + 9830400);    //  128*1024*2 =  262144
  ushort* Yl   = (ushort*)(w + 10092544);
  float*  Vf   = (float*)(w + 10354688);    //  524288
  ushort* Vh   = (ushort*)(w + 10878976);   //  262144
  ushort* Vl   = (ushort*)(w + 11141120);
  float*  aB   = (float*)(w + 11403264);    //  128*16*512*4 = 4194304
  float*  pdB  = (float*)(w + 15597568);    // 4194304
  ushort* Dh   = (ushort*)(w + 19791872);   // 2097152
  ushort* Dl   = (ushort*)(w + 21889024);   // 2097152
  float*  summB= (float*)(w + 23986176);    // 32768
  float*  invxB= (float*)(w + 24018944);    // 32768
  float*  syB  = (float*)(w + 24051712);    // 8192
  float*  invyB= (float*)(w + 24059904);    // 8192
  float*  outp = (float*)d_out;

  k_cvt<<<1248, 256, 0, stream>>>(m, q, Ww, Ah, Al, Bh, Bl);
  k_gemm_mfma<<<dim3(16, 10), 256, 0, stream>>>(Ah, Al, Bh, Bl, Wb,
      Hh, Hl, HTh, HTl, Yf, Yh, Yl, summB, invxB, syB, invyB);
  // round 0
  k_corr<0><<<dim3(2, 8, 16), 256, 0, stream>>>(Hh, Hl, Yh, Yl, Vh, Vl,
      summB, invxB, syB, invyB, aB, pdB);
  k_softmax<1><<<256, 256, 0, stream>>>(aB, pdB, Dh, Dl);
  k_hatv<0><<<128, 256, 0, stream>>>(Dh, Dl, HTh, HTl, Vf, Vh, Vl,
      Yf, Yh, Yl, syB, invyB, outp);
  // round 1
  k_corr<1><<<dim3(2, 8, 16), 256, 0, stream>>>(Hh, Hl, Yh, Yl, Vh, Vl,
      summB, invxB, syB, invyB, aB, pdB);
  k_softmax<0><<<256, 256, 0, stream>>>(aB, pdB, Dh, Dl);
  k_hatv<1><<<128, 256, 0, stream>>>(Dh, Dl, HTh, HTl, Vf, Vh, Vl,
      Yf, Yh, Yl, syB, invyB, outp);
  // round 2 (final)
  k_corr<1><<<dim3(2, 8, 16), 256, 0, stream>>>(Hh, Hl, Yh, Yl, Vh, Vl,
      summB, invxB, syB, invyB, aB, pdB);
  k_softmax<0><<<256, 256, 0, stream>>>(aB, pdB, Dh, Dl);
  k_hatv<2><<<128, 256, 0, stream>>>(Dh, Dl, HTh, HTl, Vf, Vh, Vl,
      Yf, Yh, Yl, syB, invyB, outp);
}